// Round 1
// baseline (1056.674 us; speedup 1.0000x reference)
//
#include <hip/hip_runtime.h>
#include <hip/hip_bf16.h>

#define N_NODES 30000
#define N_EDGES 480000
#define D_IN    1000
#define NHEAD   8
#define F_HID   32
#define D_EMB   64
#define NEG_SLOPE 0.2f

typedef __attribute__((ext_vector_type(4))) float  f32x4;
typedef __attribute__((ext_vector_type(8))) __bf16 bf16x8;

// ---------------------------------------------------------------------------
// Generic bf16-MFMA GEMM: C[M,N] = A[M,K] @ B[K,N] (+bias) (+relu)
// BM=64, BN=256 (4 waves, each 64x64), BK=32, 256 threads.
// A,B fp32 in global; converted to bf16 while staging to LDS; fp32 accumulate.
// ---------------------------------------------------------------------------
__global__ __launch_bounds__(256) void mfma_gemm(
    const float* __restrict__ A, const float* __restrict__ B,
    float* __restrict__ C, const float* __restrict__ bias,
    int M, int N, int K, int lda, int ldb, int ldc, int relu)
{
    __shared__ __bf16 As[64][40];    // padded stride 40 (80B) to break conflicts
    __shared__ __bf16 Bs[256][40];   // B stored transposed: Bs[n][k]

    const int tid  = threadIdx.x;
    const int bm   = blockIdx.x * 64;
    const int bn   = blockIdx.y * 256;
    const int w    = tid >> 6;
    const int lane = tid & 63;
    const int quad = lane >> 4;
    const int l16  = lane & 15;

    f32x4 acc[4][4];
    #pragma unroll
    for (int i = 0; i < 4; i++)
        #pragma unroll
        for (int j = 0; j < 4; j++)
            acc[i][j] = (f32x4){0.f, 0.f, 0.f, 0.f};

    const int ar = tid >> 2;         // 0..63 : A tile row
    const int ac = (tid & 3) * 8;    // 0,8,16,24 : A tile col group

    for (int k0 = 0; k0 < K; k0 += 32) {
        // ---- stage A tile (64 x 32) ----
        {
            int row = bm + ar;
            float v[8];
            if (row < M && (k0 + ac + 7) < K) {
                const f32x4* p = (const f32x4*)(A + (size_t)row * lda + k0 + ac);
                f32x4 v0 = p[0], v1 = p[1];
                v[0]=v0.x; v[1]=v0.y; v[2]=v0.z; v[3]=v0.w;
                v[4]=v1.x; v[5]=v1.y; v[6]=v1.z; v[7]=v1.w;
            } else {
                #pragma unroll
                for (int j = 0; j < 8; j++) {
                    int k = k0 + ac + j;
                    v[j] = (row < M && k < K) ? A[(size_t)row * lda + k] : 0.0f;
                }
            }
            bf16x8 pk;
            #pragma unroll
            for (int j = 0; j < 8; j++) pk[j] = (__bf16)v[j];
            *(bf16x8*)&As[ar][ac] = pk;
        }
        // ---- stage B tile transposed (32 x 256 -> Bs[n][k]) ----
        {
            int n = bn + tid;
            #pragma unroll
            for (int kk0 = 0; kk0 < 32; kk0 += 8) {
                float v[8];
                #pragma unroll
                for (int j = 0; j < 8; j++) {
                    int k = k0 + kk0 + j;
                    v[j] = (k < K && n < N) ? B[(size_t)k * ldb + n] : 0.0f;
                }
                bf16x8 pk;
                #pragma unroll
                for (int j = 0; j < 8; j++) pk[j] = (__bf16)v[j];
                *(bf16x8*)&Bs[tid][kk0] = pk;
            }
        }
        __syncthreads();

        bf16x8 af[4], bfr[4];
        #pragma unroll
        for (int mt = 0; mt < 4; mt++)
            af[mt] = *(const bf16x8*)&As[mt * 16 + l16][quad * 8];
        #pragma unroll
        for (int nt = 0; nt < 4; nt++)
            bfr[nt] = *(const bf16x8*)&Bs[w * 64 + nt * 16 + l16][quad * 8];

        #pragma unroll
        for (int mt = 0; mt < 4; mt++)
            #pragma unroll
            for (int nt = 0; nt < 4; nt++)
                acc[mt][nt] = __builtin_amdgcn_mfma_f32_16x16x32_bf16(
                    af[mt], bfr[nt], acc[mt][nt], 0, 0, 0);
        __syncthreads();
    }

    // ---- epilogue: D row = quad*4 + r, col = lane&15 ----
    #pragma unroll
    for (int nt = 0; nt < 4; nt++) {
        int col = bn + w * 64 + nt * 16 + l16;
        if (col >= N) continue;
        float bv = bias ? bias[col] : 0.0f;
        #pragma unroll
        for (int mt = 0; mt < 4; mt++) {
            int row0 = bm + mt * 16 + quad * 4;
            #pragma unroll
            for (int rr = 0; rr < 4; rr++) {
                int row = row0 + rr;
                if (row < M) {
                    float v = acc[mt][nt][rr] + bv;
                    if (relu) v = v > 0.f ? v : 0.f;
                    C[(size_t)row * ldc + col] = v;
                }
            }
        }
    }
}

// ---------------------------------------------------------------------------
// Attention scores: a_s[n,h] = h[n,h,:].att_src[h,:], a_d similarly.
// ---------------------------------------------------------------------------
__global__ __launch_bounds__(256) void att_scores(
    const float* __restrict__ h, const float* __restrict__ att_src,
    const float* __restrict__ att_dst, float* __restrict__ a_s,
    float* __restrict__ a_d)
{
    int i = blockIdx.x * 256 + threadIdx.x;     // i over N_NODES*NHEAD
    if (i >= N_NODES * NHEAD) return;
    int hh = i & 7;
    const f32x4* hp = (const f32x4*)(h + (size_t)i * F_HID);
    const f32x4* sp = (const f32x4*)(att_src + hh * F_HID);
    const f32x4* dp = (const f32x4*)(att_dst + hh * F_HID);
    float s = 0.f, d = 0.f;
    #pragma unroll
    for (int j = 0; j < 8; j++) {
        f32x4 hv = hp[j], sv = sp[j], dv = dp[j];
        s += hv.x*sv.x + hv.y*sv.y + hv.z*sv.z + hv.w*sv.w;
        d += hv.x*dv.x + hv.y*dv.y + hv.z*dv.z + hv.w*dv.w;
    }
    a_s[i] = s;
    a_d[i] = d;
}

// ---------------------------------------------------------------------------
// CSR build
// ---------------------------------------------------------------------------
__global__ void zero_int(int* p, int n) {
    int i = blockIdx.x * 256 + threadIdx.x;
    if (i < n) p[i] = 0;
}

__global__ void count_deg(const int* __restrict__ eidx, int* __restrict__ deg) {
    int e = blockIdx.x * 256 + threadIdx.x;
    if (e < N_EDGES) atomicAdd(&deg[eidx[N_EDGES + e]], 1);
}

__global__ __launch_bounds__(1024) void scan_deg(
    const int* __restrict__ deg, int* __restrict__ row_ptr, int* __restrict__ cursor)
{
    __shared__ int sums[1024];
    const int t = threadIdx.x;
    const int PER = 30;                 // 1024*30 >= 30000
    int base = t * PER;
    int local[PER];
    int s = 0;
    #pragma unroll
    for (int j = 0; j < PER; j++) {
        int idx = base + j;
        int v = (idx < N_NODES) ? deg[idx] : 0;
        local[j] = s;
        s += v;
    }
    sums[t] = s;
    __syncthreads();
    for (int off = 1; off < 1024; off <<= 1) {
        int v = (t >= off) ? sums[t - off] : 0;
        __syncthreads();
        sums[t] += v;
        __syncthreads();
    }
    int pre = (t == 0) ? 0 : sums[t - 1];
    #pragma unroll
    for (int j = 0; j < PER; j++) {
        int idx = base + j;
        if (idx < N_NODES) {
            int v = pre + local[j];
            row_ptr[idx] = v;
            cursor[idx]  = v;
        }
    }
    if (t == 1023) row_ptr[N_NODES] = sums[1023];
}

__global__ void scatter_edges(const int* __restrict__ eidx,
                              int* __restrict__ cursor, int* __restrict__ sorted_src) {
    int e = blockIdx.x * 256 + threadIdx.x;
    if (e < N_EDGES) {
        int d = eidx[N_EDGES + e];
        int pos = atomicAdd(&cursor[d], 1);
        sorted_src[pos] = eidx[e];
    }
}

// ---------------------------------------------------------------------------
// GAT aggregation: one wave per destination node.
// Phase 1: denom[h] = sum over incoming edges (incl self) of exp(leaky(a_s[src]+a_d[n]))
// Phase 2: hgat[n] = relu( sum alpha_e * h[src_e] + bias )
// ---------------------------------------------------------------------------
__device__ __forceinline__ float leaky(float x) {
    return x > 0.f ? x : NEG_SLOPE * x;
}

__global__ __launch_bounds__(256) void gat_aggregate(
    const float* __restrict__ h, const float* __restrict__ a_s,
    const float* __restrict__ a_d, const int* __restrict__ row_ptr,
    const int* __restrict__ sorted_src, const float* __restrict__ bias,
    float* __restrict__ hgat)
{
    const int wid  = threadIdx.x >> 6;
    const int lane = threadIdx.x & 63;
    const int n = blockIdx.x * 4 + wid;
    if (n >= N_NODES) return;

    const int start = row_ptr[n];
    const int degn  = row_ptr[n + 1] - start;

    // ---- phase 1: denominators (lane = el*8 + h8) ----
    const int h8 = lane & 7;
    const int el = lane >> 3;
    const float adn = a_d[n * NHEAD + h8];
    float dsum = 0.f;
    if (el == 0) dsum = __expf(leaky(a_s[n * NHEAD + h8] + adn));  // self loop
    for (int b = 0; b < degn; b += 8) {
        int i = b + el;
        if (i < degn) {
            int s = sorted_src[start + i];
            dsum += __expf(leaky(a_s[s * NHEAD + h8] + adn));
        }
    }
    dsum += __shfl_xor(dsum, 8);
    dsum += __shfl_xor(dsum, 16);
    dsum += __shfl_xor(dsum, 32);

    // ---- phase 2: weighted aggregation (lane covers head hh, f = fo..fo+3) ----
    const int hh = lane >> 3;
    const int fo = (lane & 7) * 4;
    const float denom = __shfl(dsum, hh);
    const float adn2 = a_d[n * NHEAD + hh];

    f32x4 acc;
    {
        float alpha = __expf(leaky(a_s[n * NHEAD + hh] + adn2)) / denom;
        f32x4 hv = *(const f32x4*)(h + (size_t)n * 256 + hh * F_HID + fo);
        acc.x = hv.x * alpha; acc.y = hv.y * alpha;
        acc.z = hv.z * alpha; acc.w = hv.w * alpha;
    }
    for (int i = 0; i < degn; i++) {
        int s = sorted_src[start + i];
        float alpha = __expf(leaky(a_s[s * NHEAD + hh] + adn2)) / denom;
        f32x4 hv = *(const f32x4*)(h + (size_t)s * 256 + hh * F_HID + fo);
        acc.x += hv.x * alpha; acc.y += hv.y * alpha;
        acc.z += hv.z * alpha; acc.w += hv.w * alpha;
    }
    f32x4 bv = *(const f32x4*)(bias + lane * 4);
    f32x4 o;
    o.x = acc.x + bv.x; o.y = acc.y + bv.y;
    o.z = acc.z + bv.z; o.w = acc.w + bv.w;
    o.x = o.x > 0.f ? o.x : 0.f;
    o.y = o.y > 0.f ? o.y : 0.f;
    o.z = o.z > 0.f ? o.z : 0.f;
    o.w = o.w > 0.f ? o.w : 0.f;
    *(f32x4*)(hgat + (size_t)n * 256 + lane * 4) = o;
}

// ---------------------------------------------------------------------------
extern "C" void kernel_launch(void* const* d_in, const int* in_sizes, int n_in,
                              void* d_out, int out_size, void* d_ws, size_t ws_size,
                              hipStream_t stream)
{
    const float* x        = (const float*)d_in[0];
    const int*   eidx     = (const int*)  d_in[1];
    /* d_in[2] edge_weight: unused by reference */
    const float* W        = (const float*)d_in[3];
    const float* att_src  = (const float*)d_in[4];
    const float* att_dst  = (const float*)d_in[5];
    const float* bias_gat = (const float*)d_in[6];
    const float* emb_W    = (const float*)d_in[7];
    const float* emb_b    = (const float*)d_in[8];
    const float* dec_W1   = (const float*)d_in[9];
    const float* dec_b1   = (const float*)d_in[10];
    const float* dec_W2   = (const float*)d_in[11];
    const float* dec_b2   = (const float*)d_in[12];

    float* out   = (float*)d_out;
    float* recon = out;                             // [30000,1000]
    float* z     = out + (size_t)N_NODES * D_IN;    // [30000,64]

    float* ws   = (float*)d_ws;
    float* h    = ws;                               // 30000*256
    float* hgat = h    + (size_t)N_NODES * 256;     // 30000*256
    float* a_s  = hgat + (size_t)N_NODES * 256;     // 30000*8
    float* a_d  = a_s  + N_NODES * NHEAD;           // 30000*8
    float* dbuf = a_d  + N_NODES * NHEAD;           // 30000*32
    int* sorted_src = (int*)(dbuf + (size_t)N_NODES * F_HID);  // 480000
    int* deg     = sorted_src + N_EDGES;            // 30000
    int* row_ptr = deg + N_NODES;                   // 30001
    int* cursor  = row_ptr + N_NODES + 1;           // 30000

    const int MB = (N_NODES + 63) / 64;             // 469

    // 1. h = x @ W               [30000,1000]x[1000,256]
    mfma_gemm<<<dim3(MB, 1), 256, 0, stream>>>(
        x, W, h, nullptr, N_NODES, 256, D_IN, D_IN, 256, 256, 0);

    // 2. attention scores
    att_scores<<<(N_NODES * NHEAD + 255) / 256, 256, 0, stream>>>(
        h, att_src, att_dst, a_s, a_d);

    // 3. CSR build
    zero_int<<<(N_NODES + 255) / 256, 256, 0, stream>>>(deg, N_NODES);
    count_deg<<<(N_EDGES + 255) / 256, 256, 0, stream>>>(eidx, deg);
    scan_deg<<<1, 1024, 0, stream>>>(deg, row_ptr, cursor);
    scatter_edges<<<(N_EDGES + 255) / 256, 256, 0, stream>>>(eidx, cursor, sorted_src);

    // 4. GAT aggregation (+bias_gat, relu) -> hgat
    gat_aggregate<<<N_NODES / 4, 256, 0, stream>>>(
        h, a_s, a_d, row_ptr, sorted_src, bias_gat, hgat);

    // 5. z = hgat @ emb_W + emb_b        [30000,256]x[256,64]
    mfma_gemm<<<dim3(MB, 1), 256, 0, stream>>>(
        hgat, emb_W, z, emb_b, N_NODES, D_EMB, 256, 256, D_EMB, D_EMB, 0);

    // 6. d = relu(z @ dec_W1 + dec_b1)   [30000,64]x[64,32]
    mfma_gemm<<<dim3(MB, 1), 256, 0, stream>>>(
        z, dec_W1, dbuf, dec_b1, N_NODES, F_HID, D_EMB, D_EMB, F_HID, F_HID, 1);

    // 7. recon = d @ dec_W2 + dec_b2     [30000,32]x[32,1000]
    mfma_gemm<<<dim3(MB, 4), 256, 0, stream>>>(
        dbuf, dec_W2, recon, dec_b2, N_NODES, D_IN, F_HID, F_HID, D_IN, D_IN, 0);
}

// Round 2
// 548.431 us; speedup vs baseline: 1.9267x; 1.9267x over previous
//
#include <hip/hip_runtime.h>
#include <hip/hip_bf16.h>

#define N_NODES 30000
#define N_EDGES 480000
#define D_IN    1000
#define NHEAD   8
#define F_HID   32
#define D_EMB   64
#define NEG_SLOPE 0.2f

typedef __attribute__((ext_vector_type(4))) float  f32x4;
typedef __attribute__((ext_vector_type(8))) __bf16 bf16x8;
typedef __attribute__((ext_vector_type(4))) __bf16 bf16x4;

// ---------------------------------------------------------------------------
// fp32 -> bf16 bulk convert (n divisible by 8 for our uses; tail handled)
// ---------------------------------------------------------------------------
__global__ __launch_bounds__(256) void cvt_f32_bf16(
    const float* __restrict__ s, __bf16* __restrict__ d, int n)
{
    int i = (blockIdx.x * 256 + threadIdx.x) * 8;
    if (i + 8 <= n) {
        f32x4 a = *(const f32x4*)(s + i);
        f32x4 b = *(const f32x4*)(s + i + 4);
        bf16x8 o;
        o[0]=(__bf16)a.x; o[1]=(__bf16)a.y; o[2]=(__bf16)a.z; o[3]=(__bf16)a.w;
        o[4]=(__bf16)b.x; o[5]=(__bf16)b.y; o[6]=(__bf16)b.z; o[7]=(__bf16)b.w;
        *(bf16x8*)(d + i) = o;
    } else {
        for (; i < n; i++) d[i] = (__bf16)s[i];
    }
}

// fp32 [K,N] -> bf16 [N,K] (transpose + convert; small weights, L2-resident)
__global__ __launch_bounds__(256) void cvt_transpose(
    const float* __restrict__ src, __bf16* __restrict__ dst, int K, int N)
{
    int i = blockIdx.x * 256 + threadIdx.x;
    if (i < K * N) {
        int k = i / N, n = i - k * N;
        dst[(size_t)n * K + k] = (__bf16)src[i];
    }
}

// ---------------------------------------------------------------------------
// bf16 MFMA GEMM, m97 structure: C[M,N] = A[M,K] @ Bt[N,K]^T
// 256 threads = 4 waves (2m x 2n). BM=128. BK=32. global_load_lds staging.
// XOR chunk swizzle (slot s at row r holds global k-chunk s^(r&3)).
// ---------------------------------------------------------------------------
__device__ __forceinline__ void stage_tile(
    __bf16* lds, const __bf16* __restrict__ g, int base, int maxr,
    int K, int k0, int rows, int w, int lane)
{
    const int rsub = lane >> 2;
    const int c    = lane & 3;
    for (int off = w * 1024; off < rows * 64; off += 4096) {
        int r  = (off >> 6) + rsub;
        int gr = base + r; gr = gr > maxr ? maxr : gr;
        int chunk = c ^ (r & 3);
        const __bf16* gp = g + (size_t)gr * K + k0 + chunk * 8;
        __builtin_amdgcn_global_load_lds(
            (const __attribute__((address_space(1))) void*)gp,
            (__attribute__((address_space(3))) void*)((char*)lds + off),
            16, 0, 0);
    }
}

__device__ __forceinline__ void stage_tail(
    __bf16* lds, const __bf16* __restrict__ g, int base, int maxr,
    int K, int k0, int rows, int tid)
{
    for (int r = tid; r < rows; r += 256) {
        int gr = base + r; gr = gr > maxr ? maxr : gr;
        const __bf16* gp = g + (size_t)gr * K;
        #pragma unroll
        for (int j = 0; j < 32; j++) {
            int k = k0 + j;
            int s = (j >> 3) ^ (r & 3);
            lds[r * 32 + s * 8 + (j & 7)] = (k < K) ? gp[k] : (__bf16)0.0f;
        }
    }
}

template<int BM, int BN, int RELU>
__global__ __launch_bounds__(256) void gemm_bf16(
    const __bf16* __restrict__ A, const __bf16* __restrict__ Bt,
    float* __restrict__ Cf, __bf16* __restrict__ Cb,
    const float* __restrict__ bias, int M, int Nn, int K)
{
    constexpr int MT = BM / 32;       // 16-tiles per wave (m)
    constexpr int NT = BN / 32;       // 16-tiles per wave (n)
    __shared__ __align__(16) __bf16 As[BM * 32];
    __shared__ __align__(16) __bf16 Bs[BN * 32];

    const int tid  = threadIdx.x;
    const int w    = tid >> 6, lane = tid & 63;
    const int wm   = w >> 1,   wn   = w & 1;
    const int quad = lane >> 4, l16 = lane & 15;
    const int bm = blockIdx.x * BM, bn = blockIdx.y * BN;

    f32x4 acc[MT][NT];
    #pragma unroll
    for (int i = 0; i < MT; i++)
        #pragma unroll
        for (int j = 0; j < NT; j++)
            acc[i][j] = (f32x4){0.f, 0.f, 0.f, 0.f};

    for (int k0 = 0; k0 < K; k0 += 32) {
        if (k0 + 32 <= K) {
            stage_tile(As, A,  bm, M  - 1, K, k0, BM, w, lane);
            stage_tile(Bs, Bt, bn, Nn - 1, K, k0, BN, w, lane);
        } else {
            stage_tail(As, A,  bm, M  - 1, K, k0, BM, tid);
            stage_tail(Bs, Bt, bn, Nn - 1, K, k0, BN, tid);
        }
        __syncthreads();

        bf16x8 af[MT], bfr[NT];
        #pragma unroll
        for (int mt = 0; mt < MT; mt++) {
            int r = wm * 64 + mt * 16 + l16;
            af[mt] = *(const bf16x8*)&As[r * 32 + (quad ^ (r & 3)) * 8];
        }
        #pragma unroll
        for (int nt = 0; nt < NT; nt++) {
            int r = wn * (NT * 16) + nt * 16 + l16;
            bfr[nt] = *(const bf16x8*)&Bs[r * 32 + (quad ^ (r & 3)) * 8];
        }
        #pragma unroll
        for (int mt = 0; mt < MT; mt++)
            #pragma unroll
            for (int nt = 0; nt < NT; nt++)
                acc[mt][nt] = __builtin_amdgcn_mfma_f32_16x16x32_bf16(
                    af[mt], bfr[nt], acc[mt][nt], 0, 0, 0);
        __syncthreads();
    }

    // epilogue: D row = quad*4 + rr, col = l16 within each 16x16 tile
    #pragma unroll
    for (int nt = 0; nt < NT; nt++) {
        int col = bn + wn * (NT * 16) + nt * 16 + l16;
        if (col >= Nn) continue;
        float bv = bias ? bias[col] : 0.0f;
        #pragma unroll
        for (int mt = 0; mt < MT; mt++) {
            int row0 = bm + wm * 64 + mt * 16 + quad * 4;
            #pragma unroll
            for (int rr = 0; rr < 4; rr++) {
                int row = row0 + rr;
                if (row < M) {
                    float v = acc[mt][nt][rr] + bv;
                    if (RELU) v = v > 0.f ? v : 0.f;
                    if (Cf) Cf[(size_t)row * Nn + col] = v;
                    if (Cb) Cb[(size_t)row * Nn + col] = (__bf16)v;
                }
            }
        }
    }
}

// ---------------------------------------------------------------------------
// Attention scores: a_s[n,h] = h[n,h,:].att_src[h,:], a_d similarly.
// ---------------------------------------------------------------------------
__global__ __launch_bounds__(256) void att_scores(
    const float* __restrict__ h, const float* __restrict__ att_src,
    const float* __restrict__ att_dst, float* __restrict__ a_s,
    float* __restrict__ a_d)
{
    int i = blockIdx.x * 256 + threadIdx.x;
    if (i >= N_NODES * NHEAD) return;
    int hh = i & 7;
    const f32x4* hp = (const f32x4*)(h + (size_t)i * F_HID);
    const f32x4* sp = (const f32x4*)(att_src + hh * F_HID);
    const f32x4* dp = (const f32x4*)(att_dst + hh * F_HID);
    float s = 0.f, d = 0.f;
    #pragma unroll
    for (int j = 0; j < 8; j++) {
        f32x4 hv = hp[j], sv = sp[j], dv = dp[j];
        s += hv.x*sv.x + hv.y*sv.y + hv.z*sv.z + hv.w*sv.w;
        d += hv.x*dv.x + hv.y*dv.y + hv.z*dv.z + hv.w*dv.w;
    }
    a_s[i] = s;
    a_d[i] = d;
}

// ---------------------------------------------------------------------------
// CSR build
// ---------------------------------------------------------------------------
__global__ void zero_int(int* p, int n) {
    int i = blockIdx.x * 256 + threadIdx.x;
    if (i < n) p[i] = 0;
}

__global__ void count_deg(const int* __restrict__ eidx, int* __restrict__ deg) {
    int e = blockIdx.x * 256 + threadIdx.x;
    if (e < N_EDGES) atomicAdd(&deg[eidx[N_EDGES + e]], 1);
}

__global__ __launch_bounds__(1024) void scan_deg(
    const int* __restrict__ deg, int* __restrict__ row_ptr, int* __restrict__ cursor)
{
    __shared__ int sums[1024];
    const int t = threadIdx.x;
    const int PER = 30;
    int base = t * PER;
    int local[PER];
    int s = 0;
    #pragma unroll
    for (int j = 0; j < PER; j++) {
        int idx = base + j;
        int v = (idx < N_NODES) ? deg[idx] : 0;
        local[j] = s;
        s += v;
    }
    sums[t] = s;
    __syncthreads();
    for (int off = 1; off < 1024; off <<= 1) {
        int v = (t >= off) ? sums[t - off] : 0;
        __syncthreads();
        sums[t] += v;
        __syncthreads();
    }
    int pre = (t == 0) ? 0 : sums[t - 1];
    #pragma unroll
    for (int j = 0; j < PER; j++) {
        int idx = base + j;
        if (idx < N_NODES) {
            int v = pre + local[j];
            row_ptr[idx] = v;
            cursor[idx]  = v;
        }
    }
    if (t == 1023) row_ptr[N_NODES] = sums[1023];
}

__global__ void scatter_edges(const int* __restrict__ eidx,
                              int* __restrict__ cursor, int* __restrict__ sorted_src) {
    int e = blockIdx.x * 256 + threadIdx.x;
    if (e < N_EDGES) {
        int d = eidx[N_EDGES + e];
        int pos = atomicAdd(&cursor[d], 1);
        sorted_src[pos] = eidx[e];
    }
}

// ---------------------------------------------------------------------------
// GAT aggregation: one wave per destination node. Output bf16.
// ---------------------------------------------------------------------------
__device__ __forceinline__ float leaky(float x) {
    return x > 0.f ? x : NEG_SLOPE * x;
}

__global__ __launch_bounds__(256) void gat_aggregate(
    const float* __restrict__ h, const float* __restrict__ a_s,
    const float* __restrict__ a_d, const int* __restrict__ row_ptr,
    const int* __restrict__ sorted_src, const float* __restrict__ bias,
    __bf16* __restrict__ hgatb)
{
    const int wid  = threadIdx.x >> 6;
    const int lane = threadIdx.x & 63;
    const int n = blockIdx.x * 4 + wid;
    if (n >= N_NODES) return;

    const int start = row_ptr[n];
    const int degn  = row_ptr[n + 1] - start;

    // phase 1: denominators (lane = el*8 + h8)
    const int h8 = lane & 7;
    const int el = lane >> 3;
    const float adn = a_d[n * NHEAD + h8];
    float dsum = 0.f;
    if (el == 0) dsum = __expf(leaky(a_s[n * NHEAD + h8] + adn));
    for (int b = 0; b < degn; b += 8) {
        int i = b + el;
        if (i < degn) {
            int s = sorted_src[start + i];
            dsum += __expf(leaky(a_s[s * NHEAD + h8] + adn));
        }
    }
    dsum += __shfl_xor(dsum, 8);
    dsum += __shfl_xor(dsum, 16);
    dsum += __shfl_xor(dsum, 32);

    // phase 2: aggregation (lane -> head hh, feats fo..fo+3)
    const int hh = lane >> 3;
    const int fo = (lane & 7) * 4;
    const float denom = __shfl(dsum, hh);
    const float adn2 = a_d[n * NHEAD + hh];

    f32x4 acc;
    {
        float alpha = __expf(leaky(a_s[n * NHEAD + hh] + adn2)) / denom;
        f32x4 hv = *(const f32x4*)(h + (size_t)n * 256 + hh * F_HID + fo);
        acc.x = hv.x * alpha; acc.y = hv.y * alpha;
        acc.z = hv.z * alpha; acc.w = hv.w * alpha;
    }
    for (int i = 0; i < degn; i++) {
        int s = sorted_src[start + i];
        float alpha = __expf(leaky(a_s[s * NHEAD + hh] + adn2)) / denom;
        f32x4 hv = *(const f32x4*)(h + (size_t)s * 256 + hh * F_HID + fo);
        acc.x += hv.x * alpha; acc.y += hv.y * alpha;
        acc.z += hv.z * alpha; acc.w += hv.w * alpha;
    }
    f32x4 bv = *(const f32x4*)(bias + lane * 4);
    float o0 = acc.x + bv.x, o1 = acc.y + bv.y, o2 = acc.z + bv.z, o3 = acc.w + bv.w;
    o0 = o0 > 0.f ? o0 : 0.f;
    o1 = o1 > 0.f ? o1 : 0.f;
    o2 = o2 > 0.f ? o2 : 0.f;
    o3 = o3 > 0.f ? o3 : 0.f;
    bf16x4 ob;
    ob[0] = (__bf16)o0; ob[1] = (__bf16)o1; ob[2] = (__bf16)o2; ob[3] = (__bf16)o3;
    *(bf16x4*)(hgatb + (size_t)n * 256 + lane * 4) = ob;
}

// ---------------------------------------------------------------------------
extern "C" void kernel_launch(void* const* d_in, const int* in_sizes, int n_in,
                              void* d_out, int out_size, void* d_ws, size_t ws_size,
                              hipStream_t stream)
{
    const float* x        = (const float*)d_in[0];
    const int*   eidx     = (const int*)  d_in[1];
    const float* W        = (const float*)d_in[3];
    const float* att_src  = (const float*)d_in[4];
    const float* att_dst  = (const float*)d_in[5];
    const float* bias_gat = (const float*)d_in[6];
    const float* emb_W    = (const float*)d_in[7];
    const float* emb_b    = (const float*)d_in[8];
    const float* dec_W1   = (const float*)d_in[9];
    const float* dec_b1   = (const float*)d_in[10];
    const float* dec_W2   = (const float*)d_in[11];
    const float* dec_b2   = (const float*)d_in[12];

    float* out   = (float*)d_out;
    float* recon = out;                             // [30000,1000] fp32
    float* z     = out + (size_t)N_NODES * D_IN;    // [30000,64]   fp32

    // xb (bf16 x, 60MB) lives in the recon region of d_out (dead before gemm4).
    __bf16* xb = (__bf16*)recon;

    // ws layout (byte offsets, 256-aligned)
    char* ws = (char*)d_ws;
    size_t o = 0;
    auto alloc = [&](size_t bytes) { char* p = ws + o; o = (o + bytes + 255) & ~(size_t)255; return p; };
    float*  h       = (float*) alloc((size_t)N_NODES * 256 * 4);   // 30.72MB
    __bf16* WbT     = (__bf16*)alloc((size_t)256 * D_IN * 2);      // [256][1000]
    __bf16* embT    = (__bf16*)alloc((size_t)D_EMB * 256 * 2);     // [64][256]
    __bf16* d1T     = (__bf16*)alloc((size_t)F_HID * D_EMB * 2);   // [32][64]
    __bf16* d2T     = (__bf16*)alloc((size_t)D_IN * F_HID * 2);    // [1000][32]
    __bf16* hgatb   = (__bf16*)alloc((size_t)N_NODES * 256 * 2);   // 15.36MB
    __bf16* zb      = (__bf16*)alloc((size_t)N_NODES * D_EMB * 2); // 3.84MB
    __bf16* dbufb   = (__bf16*)alloc((size_t)N_NODES * F_HID * 2); // 1.92MB
    float*  a_s     = (float*) alloc((size_t)N_NODES * NHEAD * 4);
    float*  a_d     = (float*) alloc((size_t)N_NODES * NHEAD * 4);
    int* sorted_src = (int*)   alloc((size_t)N_EDGES * 4);
    int* deg        = (int*)   alloc((size_t)N_NODES * 4);
    int* row_ptr    = (int*)   alloc((size_t)(N_NODES + 1) * 4);
    int* cursor     = (int*)   alloc((size_t)N_NODES * 4);

    const int MB = (N_NODES + 127) / 128;           // 235

    // 0. converts
    cvt_f32_bf16<<<(N_NODES * D_IN / 8 + 255) / 256, 256, 0, stream>>>(
        x, xb, N_NODES * D_IN);
    cvt_transpose<<<(D_IN * 256 + 255) / 256, 256, 0, stream>>>(W, WbT, D_IN, 256);
    cvt_transpose<<<(256 * D_EMB + 255) / 256, 256, 0, stream>>>(emb_W, embT, 256, D_EMB);
    cvt_transpose<<<(D_EMB * F_HID + 255) / 256, 256, 0, stream>>>(dec_W1, d1T, D_EMB, F_HID);
    cvt_transpose<<<(F_HID * D_IN + 255) / 256, 256, 0, stream>>>(dec_W2, d2T, F_HID, D_IN);

    // 1. h = x @ W    [30000,1000]x[1000,256] -> fp32 h
    gemm_bf16<128, 128, 0><<<dim3(MB, 2), 256, 0, stream>>>(
        xb, WbT, h, (__bf16*)nullptr, (const float*)nullptr, N_NODES, 256, D_IN);

    // 2. attention scores
    att_scores<<<(N_NODES * NHEAD + 255) / 256, 256, 0, stream>>>(
        h, att_src, att_dst, a_s, a_d);

    // 3. CSR build
    zero_int<<<(N_NODES + 255) / 256, 256, 0, stream>>>(deg, N_NODES);
    count_deg<<<(N_EDGES + 255) / 256, 256, 0, stream>>>(eidx, deg);
    scan_deg<<<1, 1024, 0, stream>>>(deg, row_ptr, cursor);
    scatter_edges<<<(N_EDGES + 255) / 256, 256, 0, stream>>>(eidx, cursor, sorted_src);

    // 4. GAT aggregation (+bias, relu) -> hgatb (bf16)
    gat_aggregate<<<N_NODES / 4, 256, 0, stream>>>(
        h, a_s, a_d, row_ptr, sorted_src, bias_gat, hgatb);

    // 5. z = hgat @ emb_W + emb_b   -> z fp32 (output) + zb bf16
    gemm_bf16<128, 64, 0><<<dim3(MB, 1), 256, 0, stream>>>(
        hgatb, embT, z, zb, emb_b, N_NODES, D_EMB, 256);

    // 6. d = relu(z @ dec_W1 + dec_b1) -> dbufb bf16
    gemm_bf16<128, 32, 1><<<dim3(MB, 1), 256, 0, stream>>>(
        zb, d1T, (float*)nullptr, dbufb, dec_b1, N_NODES, F_HID, D_EMB);

    // 7. recon = d @ dec_W2 + dec_b2  -> fp32 out (overwrites xb region)
    gemm_bf16<128, 128, 0><<<dim3(MB, 8), 256, 0, stream>>>(
        dbufb, d2T, recon, (__bf16*)nullptr, dec_b2, N_NODES, D_IN, F_HID);
}

// Round 3
// 512.887 us; speedup vs baseline: 2.0602x; 1.0693x over previous
//
#include <hip/hip_runtime.h>
#include <hip/hip_bf16.h>

#define N_NODES 30000
#define N_EDGES 480000
#define D_IN    1000
#define KPAD    1024
#define NHEAD   8
#define F_HID   32
#define D_EMB   64
#define NEG_SLOPE 0.2f

typedef __attribute__((ext_vector_type(4))) float  f32x4;
typedef __attribute__((ext_vector_type(8))) __bf16 bf16x8;
typedef __attribute__((ext_vector_type(4))) __bf16 bf16x4;

// ---------------------------------------------------------------------------
// x [30000,1000] fp32 -> xb [30000,1024] bf16 (zero-padded K)
// ---------------------------------------------------------------------------
__global__ __launch_bounds__(256) void cvt_x_pad(
    const float* __restrict__ x, __bf16* __restrict__ xb)
{
    int i = blockIdx.x * 256 + threadIdx.x;      // chunk id, 8 elems each
    if (i >= N_NODES * (KPAD / 8)) return;
    int row = i >> 7;
    int col = (i & 127) * 8;
    bf16x8 o;
    if (col < D_IN) {                            // 1000 % 8 == 0: full chunks
        const f32x4* p = (const f32x4*)(x + (size_t)row * D_IN + col);
        f32x4 a = p[0], b = p[1];
        o[0]=(__bf16)a.x; o[1]=(__bf16)a.y; o[2]=(__bf16)a.z; o[3]=(__bf16)a.w;
        o[4]=(__bf16)b.x; o[5]=(__bf16)b.y; o[6]=(__bf16)b.z; o[7]=(__bf16)b.w;
    } else {
        #pragma unroll
        for (int j = 0; j < 8; j++) o[j] = (__bf16)0.0f;
    }
    *(bf16x8*)(xb + (size_t)row * KPAD + col) = o;
}

// ---------------------------------------------------------------------------
// All weight transposes fused: fp32 [K,N] -> bf16 [N,Kpad]
// ---------------------------------------------------------------------------
__global__ __launch_bounds__(256) void cvt_weights(
    const float* __restrict__ W, const float* __restrict__ emb_W,
    const float* __restrict__ d1, const float* __restrict__ d2,
    __bf16* __restrict__ WbT, __bf16* __restrict__ embT,
    __bf16* __restrict__ d1T, __bf16* __restrict__ d2T)
{
    int i = blockIdx.x * 256 + threadIdx.x;
    if (i < 256 * KPAD) {                         // WbT [256][1024]
        int n = i >> 10, k = i & 1023;
        WbT[i] = (k < D_IN) ? (__bf16)W[(size_t)k * 256 + n] : (__bf16)0.0f;
        return;
    }
    i -= 256 * KPAD;
    if (i < D_EMB * 256) {                        // embT [64][256]
        int n = i >> 8, k = i & 255;
        embT[i] = (__bf16)emb_W[(size_t)k * D_EMB + n];
        return;
    }
    i -= D_EMB * 256;
    if (i < F_HID * D_EMB) {                      // d1T [32][64]
        int n = i >> 6, k = i & 63;
        d1T[i] = (__bf16)d1[(size_t)k * F_HID + n];
        return;
    }
    i -= F_HID * D_EMB;
    if (i < D_IN * F_HID) {                       // d2T [1000][32]
        int n = i >> 5, k = i & 31;
        d2T[i] = (__bf16)d2[(size_t)k * D_IN + n];
    }
}

// ---------------------------------------------------------------------------
// bf16 MFMA GEMM (m97 structure): C[M,N] = A[M,K] @ Bt[N,K]^T
// 256 threads = 4 waves (2m x 2n). BM=128. BK=32. global_load_lds staging.
// XOR chunk swizzle (slot s at row r holds global k-chunk s^(r&3)).
// K must be a multiple of 32 (guaranteed by padding).
// ---------------------------------------------------------------------------
__device__ __forceinline__ void stage_tile(
    __bf16* lds, const __bf16* __restrict__ g, int base, int maxr,
    int K, int k0, int rows, int w, int lane)
{
    const int rsub = lane >> 2;
    const int c    = lane & 3;
    for (int off = w * 1024; off < rows * 64; off += 4096) {
        int r  = (off >> 6) + rsub;
        int gr = base + r; gr = gr > maxr ? maxr : gr;
        int chunk = c ^ (r & 3);
        const __bf16* gp = g + (size_t)gr * K + k0 + chunk * 8;
        __builtin_amdgcn_global_load_lds(
            (const __attribute__((address_space(1))) void*)gp,
            (__attribute__((address_space(3))) void*)((char*)lds + off),
            16, 0, 0);
    }
}

template<int BM, int BN, int RELU>
__global__ __launch_bounds__(256) void gemm_bf16(
    const __bf16* __restrict__ A, const __bf16* __restrict__ Bt,
    float* __restrict__ Cf, __bf16* __restrict__ Cb,
    const float* __restrict__ bias, int M, int Nn, int K)
{
    constexpr int MT = BM / 32;
    constexpr int NT = BN / 32;
    __shared__ __align__(16) __bf16 As[BM * 32];
    __shared__ __align__(16) __bf16 Bs[BN * 32];

    const int tid  = threadIdx.x;
    const int w    = tid >> 6, lane = tid & 63;
    const int wm   = w >> 1,   wn   = w & 1;
    const int quad = lane >> 4, l16 = lane & 15;
    const int bm = blockIdx.x * BM, bn = blockIdx.y * BN;

    f32x4 acc[MT][NT];
    #pragma unroll
    for (int i = 0; i < MT; i++)
        #pragma unroll
        for (int j = 0; j < NT; j++)
            acc[i][j] = (f32x4){0.f, 0.f, 0.f, 0.f};

    for (int k0 = 0; k0 < K; k0 += 32) {
        stage_tile(As, A,  bm, M  - 1, K, k0, BM, w, lane);
        stage_tile(Bs, Bt, bn, Nn - 1, K, k0, BN, w, lane);
        __syncthreads();

        bf16x8 af[MT], bfr[NT];
        #pragma unroll
        for (int mt = 0; mt < MT; mt++) {
            int r = wm * 64 + mt * 16 + l16;
            af[mt] = *(const bf16x8*)&As[r * 32 + (quad ^ (r & 3)) * 8];
        }
        #pragma unroll
        for (int nt = 0; nt < NT; nt++) {
            int r = wn * (NT * 16) + nt * 16 + l16;
            bfr[nt] = *(const bf16x8*)&Bs[r * 32 + (quad ^ (r & 3)) * 8];
        }
        #pragma unroll
        for (int mt = 0; mt < MT; mt++)
            #pragma unroll
            for (int nt = 0; nt < NT; nt++)
                acc[mt][nt] = __builtin_amdgcn_mfma_f32_16x16x32_bf16(
                    af[mt], bfr[nt], acc[mt][nt], 0, 0, 0);
        __syncthreads();
    }

    #pragma unroll
    for (int nt = 0; nt < NT; nt++) {
        int col = bn + wn * (NT * 16) + nt * 16 + l16;
        if (col >= Nn) continue;
        float bv = bias ? bias[col] : 0.0f;
        #pragma unroll
        for (int mt = 0; mt < MT; mt++) {
            int row0 = bm + wm * 64 + mt * 16 + quad * 4;
            #pragma unroll
            for (int rr = 0; rr < 4; rr++) {
                int row = row0 + rr;
                if (row < M) {
                    float v = acc[mt][nt][rr] + bv;
                    if (RELU) v = v > 0.f ? v : 0.f;
                    if (Cf) Cf[(size_t)row * Nn + col] = v;
                    if (Cb) Cb[(size_t)row * Nn + col] = (__bf16)v;
                }
            }
        }
    }
}

// ---------------------------------------------------------------------------
// Attention scores from bf16 h.
// ---------------------------------------------------------------------------
__global__ __launch_bounds__(256) void att_scores(
    const __bf16* __restrict__ hb, const float* __restrict__ att_src,
    const float* __restrict__ att_dst, float* __restrict__ a_s,
    float* __restrict__ a_d)
{
    int i = blockIdx.x * 256 + threadIdx.x;
    if (i >= N_NODES * NHEAD) return;
    int hh = i & 7;
    const bf16x8* hp = (const bf16x8*)(hb + (size_t)i * F_HID);
    const float* sp = att_src + hh * F_HID;
    const float* dp = att_dst + hh * F_HID;
    float s = 0.f, d = 0.f;
    #pragma unroll
    for (int j = 0; j < 4; j++) {
        bf16x8 hv = hp[j];
        #pragma unroll
        for (int t = 0; t < 8; t++) {
            float f = (float)hv[t];
            s += f * sp[j * 8 + t];
            d += f * dp[j * 8 + t];
        }
    }
    a_s[i] = s;
    a_d[i] = d;
}

// ---------------------------------------------------------------------------
// CSR build
// ---------------------------------------------------------------------------
__global__ void zero_int(int* p, int n) {
    int i = blockIdx.x * 256 + threadIdx.x;
    if (i < n) p[i] = 0;
}

__global__ void count_deg(const int* __restrict__ eidx, int* __restrict__ deg) {
    int e = blockIdx.x * 256 + threadIdx.x;
    if (e < N_EDGES) atomicAdd(&deg[eidx[N_EDGES + e]], 1);
}

__global__ __launch_bounds__(1024) void scan_deg(
    const int* __restrict__ deg, int* __restrict__ row_ptr, int* __restrict__ cursor)
{
    __shared__ int sums[1024];
    const int t = threadIdx.x;
    const int PER = 30;
    int base = t * PER;
    int local[PER];
    int s = 0;
    #pragma unroll
    for (int j = 0; j < PER; j++) {
        int idx = base + j;
        int v = (idx < N_NODES) ? deg[idx] : 0;
        local[j] = s;
        s += v;
    }
    sums[t] = s;
    __syncthreads();
    for (int off = 1; off < 1024; off <<= 1) {
        int v = (t >= off) ? sums[t - off] : 0;
        __syncthreads();
        sums[t] += v;
        __syncthreads();
    }
    int pre = (t == 0) ? 0 : sums[t - 1];
    #pragma unroll
    for (int j = 0; j < PER; j++) {
        int idx = base + j;
        if (idx < N_NODES) {
            int v = pre + local[j];
            row_ptr[idx] = v;
            cursor[idx]  = v;
        }
    }
    if (t == 1023) row_ptr[N_NODES] = sums[1023];
}

__global__ void scatter_edges(const int* __restrict__ eidx,
                              int* __restrict__ cursor, int* __restrict__ sorted_src) {
    int e = blockIdx.x * 256 + threadIdx.x;
    if (e < N_EDGES) {
        int d = eidx[N_EDGES + e];
        int pos = atomicAdd(&cursor[d], 1);
        sorted_src[pos] = eidx[e];
    }
}

// ---------------------------------------------------------------------------
// GAT aggregation, single pass: out = (sum_e p_e h[src_e]) / (sum_e p_e).
// One wave per dst node; lane = (head hh, feature quad fo). No shuffles.
// ---------------------------------------------------------------------------
__device__ __forceinline__ float leaky(float x) {
    return x > 0.f ? x : NEG_SLOPE * x;
}

__global__ __launch_bounds__(256) void gat_aggregate(
    const __bf16* __restrict__ hb, const float* __restrict__ a_s,
    const float* __restrict__ a_d, const int* __restrict__ row_ptr,
    const int* __restrict__ sorted_src, const float* __restrict__ bias,
    __bf16* __restrict__ hgatb)
{
    const int wid  = threadIdx.x >> 6;
    const int lane = threadIdx.x & 63;
    const int n = blockIdx.x * 4 + wid;
    if (n >= N_NODES) return;

    const int hh = lane >> 3;
    const int fo = (lane & 7) * 4;
    const int start = row_ptr[n], end = row_ptr[n + 1];
    const float adn = a_d[n * NHEAD + hh];

    // self loop
    float p = __expf(leaky(a_s[n * NHEAD + hh] + adn));
    float denom = p;
    f32x4 acc;
    {
        bf16x4 hv = *(const bf16x4*)(hb + (size_t)n * 256 + hh * F_HID + fo);
        acc.x = p * (float)hv[0]; acc.y = p * (float)hv[1];
        acc.z = p * (float)hv[2]; acc.w = p * (float)hv[3];
    }
    for (int e = start; e < end; e++) {
        int s = sorted_src[e];
        float pe = __expf(leaky(a_s[s * NHEAD + hh] + adn));
        denom += pe;
        bf16x4 hv = *(const bf16x4*)(hb + (size_t)s * 256 + hh * F_HID + fo);
        acc.x += pe * (float)hv[0]; acc.y += pe * (float)hv[1];
        acc.z += pe * (float)hv[2]; acc.w += pe * (float)hv[3];
    }
    float inv = 1.0f / denom;
    f32x4 bv = *(const f32x4*)(bias + lane * 4);
    float o0 = acc.x * inv + bv.x, o1 = acc.y * inv + bv.y;
    float o2 = acc.z * inv + bv.z, o3 = acc.w * inv + bv.w;
    o0 = o0 > 0.f ? o0 : 0.f;
    o1 = o1 > 0.f ? o1 : 0.f;
    o2 = o2 > 0.f ? o2 : 0.f;
    o3 = o3 > 0.f ? o3 : 0.f;
    bf16x4 ob;
    ob[0] = (__bf16)o0; ob[1] = (__bf16)o1; ob[2] = (__bf16)o2; ob[3] = (__bf16)o3;
    *(bf16x4*)(hgatb + (size_t)n * 256 + lane * 4) = ob;
}

// ---------------------------------------------------------------------------
extern "C" void kernel_launch(void* const* d_in, const int* in_sizes, int n_in,
                              void* d_out, int out_size, void* d_ws, size_t ws_size,
                              hipStream_t stream)
{
    const float* x        = (const float*)d_in[0];
    const int*   eidx     = (const int*)  d_in[1];
    const float* W        = (const float*)d_in[3];
    const float* att_src  = (const float*)d_in[4];
    const float* att_dst  = (const float*)d_in[5];
    const float* bias_gat = (const float*)d_in[6];
    const float* emb_W    = (const float*)d_in[7];
    const float* emb_b    = (const float*)d_in[8];
    const float* dec_W1   = (const float*)d_in[9];
    const float* dec_b1   = (const float*)d_in[10];
    const float* dec_W2   = (const float*)d_in[11];
    const float* dec_b2   = (const float*)d_in[12];

    float* out   = (float*)d_out;
    float* recon = out;                             // [30000,1000] fp32
    float* z     = out + (size_t)N_NODES * D_IN;    // [30000,64]   fp32

    // xb (bf16 x padded to K=1024, 61.4MB) lives in the recon region of d_out
    // (dead before gemm4 overwrites it).
    __bf16* xb = (__bf16*)recon;

    char* ws = (char*)d_ws;
    size_t o = 0;
    auto alloc = [&](size_t bytes) { char* p = ws + o; o = (o + bytes + 255) & ~(size_t)255; return p; };
    __bf16* hb      = (__bf16*)alloc((size_t)N_NODES * 256 * 2);   // 15.36MB
    __bf16* WbT     = (__bf16*)alloc((size_t)256 * KPAD * 2);      // [256][1024]
    __bf16* embT    = (__bf16*)alloc((size_t)D_EMB * 256 * 2);     // [64][256]
    __bf16* d1T     = (__bf16*)alloc((size_t)F_HID * D_EMB * 2);   // [32][64]
    __bf16* d2T     = (__bf16*)alloc((size_t)D_IN * F_HID * 2);    // [1000][32]
    __bf16* hgatb   = (__bf16*)alloc((size_t)N_NODES * 256 * 2);   // 15.36MB
    __bf16* zb      = (__bf16*)alloc((size_t)N_NODES * D_EMB * 2); // 3.84MB
    __bf16* dbufb   = (__bf16*)alloc((size_t)N_NODES * F_HID * 2); // 1.92MB
    float*  a_s     = (float*) alloc((size_t)N_NODES * NHEAD * 4);
    float*  a_d     = (float*) alloc((size_t)N_NODES * NHEAD * 4);
    int* sorted_src = (int*)   alloc((size_t)N_EDGES * 4);
    int* deg        = (int*)   alloc((size_t)N_NODES * 4);
    int* row_ptr    = (int*)   alloc((size_t)(N_NODES + 1) * 4);
    int* cursor     = (int*)   alloc((size_t)N_NODES * 4);

    const int MB = (N_NODES + 127) / 128;           // 235

    // 0. converts (x pad-cvt + fused weight transposes)
    cvt_x_pad<<<(N_NODES * (KPAD / 8) + 255) / 256, 256, 0, stream>>>(x, xb);
    {
        int tot = 256 * KPAD + D_EMB * 256 + F_HID * D_EMB + D_IN * F_HID;
        cvt_weights<<<(tot + 255) / 256, 256, 0, stream>>>(
            W, emb_W, dec_W1, dec_W2, WbT, embT, d1T, d2T);
    }

    // 1. h = x @ W  -> hb bf16   [30000,1024]x[1024,256]
    gemm_bf16<128, 128, 0><<<dim3(MB, 2), 256, 0, stream>>>(
        xb, WbT, (float*)nullptr, hb, (const float*)nullptr, N_NODES, 256, KPAD);

    // 2. attention scores
    att_scores<<<(N_NODES * NHEAD + 255) / 256, 256, 0, stream>>>(
        hb, att_src, att_dst, a_s, a_d);

    // 3. CSR build
    zero_int<<<(N_NODES + 255) / 256, 256, 0, stream>>>(deg, N_NODES);
    count_deg<<<(N_EDGES + 255) / 256, 256, 0, stream>>>(eidx, deg);
    scan_deg<<<1, 1024, 0, stream>>>(deg, row_ptr, cursor);
    scatter_edges<<<(N_EDGES + 255) / 256, 256, 0, stream>>>(eidx, cursor, sorted_src);

    // 4. GAT aggregation (single pass, +bias, relu) -> hgatb bf16
    gat_aggregate<<<N_NODES / 4, 256, 0, stream>>>(
        hb, a_s, a_d, row_ptr, sorted_src, bias_gat, hgatb);

    // 5. z = hgat @ emb_W + emb_b   -> z fp32 (output) + zb bf16
    gemm_bf16<128, 64, 0><<<dim3(MB, 1), 256, 0, stream>>>(
        hgatb, embT, z, zb, emb_b, N_NODES, D_EMB, 256);

    // 6. d = relu(z @ dec_W1 + dec_b1) -> dbufb bf16
    gemm_bf16<128, 32, 1><<<dim3(MB, 1), 256, 0, stream>>>(
        zb, d1T, (float*)nullptr, dbufb, dec_b1, N_NODES, F_HID, D_EMB);

    // 7. recon = d @ dec_W2 + dec_b2  -> fp32 out (overwrites xb region)
    gemm_bf16<128, 128, 0><<<dim3(MB, 8), 256, 0, stream>>>(
        dbufb, d2T, recon, (__bf16*)nullptr, dec_b2, N_NODES, D_IN, F_HID);
}

// Round 4
// 413.494 us; speedup vs baseline: 2.5555x; 1.2404x over previous
//
#include <hip/hip_runtime.h>
#include <hip/hip_bf16.h>

#define N_NODES 30000
#define N_EDGES 480000
#define D_IN    1000
#define KPAD    1024
#define NHEAD   8
#define F_HID   32
#define D_EMB   64
#define NEG_SLOPE 0.2f
#define MAXDEG  64

typedef __attribute__((ext_vector_type(4))) float  f32x4;
typedef __attribute__((ext_vector_type(8))) __bf16 bf16x8;
typedef __attribute__((ext_vector_type(4))) __bf16 bf16x4;

// ---------------------------------------------------------------------------
// Fused convert kernel: x pad-cvt | weight transposes | zero cnt
// ---------------------------------------------------------------------------
#define XB_BLOCKS 15000                       // 30000*128/256
#define WT_TOT    (256*KPAD + D_EMB*256 + F_HID*D_EMB + D_IN*F_HID)
#define WT_BLOCKS ((WT_TOT + 255) / 256)      // 1221
#define ZC_BLOCKS ((N_NODES + 255) / 256)     // 118

__global__ __launch_bounds__(256) void cvt_all(
    const float* __restrict__ x, const float* __restrict__ W,
    const float* __restrict__ emb_W, const float* __restrict__ d1,
    const float* __restrict__ d2,
    __bf16* __restrict__ xb, __bf16* __restrict__ WbT,
    __bf16* __restrict__ embT, __bf16* __restrict__ d1T,
    __bf16* __restrict__ d2T, int* __restrict__ cnt)
{
    int b = blockIdx.x;
    if (b < XB_BLOCKS) {
        int i = b * 256 + threadIdx.x;        // chunk id, 8 elems
        int row = i >> 7;
        int col = (i & 127) * 8;
        bf16x8 o;
        if (col < D_IN) {
            const f32x4* p = (const f32x4*)(x + (size_t)row * D_IN + col);
            f32x4 a = p[0], bb = p[1];
            o[0]=(__bf16)a.x;  o[1]=(__bf16)a.y;  o[2]=(__bf16)a.z;  o[3]=(__bf16)a.w;
            o[4]=(__bf16)bb.x; o[5]=(__bf16)bb.y; o[6]=(__bf16)bb.z; o[7]=(__bf16)bb.w;
        } else {
            #pragma unroll
            for (int j = 0; j < 8; j++) o[j] = (__bf16)0.0f;
        }
        *(bf16x8*)(xb + (size_t)row * KPAD + col) = o;
        return;
    }
    b -= XB_BLOCKS;
    if (b < WT_BLOCKS) {
        int i = b * 256 + threadIdx.x;
        if (i < 256 * KPAD) {                 // WbT [256][1024]
            int n = i >> 10, k = i & 1023;
            WbT[i] = (k < D_IN) ? (__bf16)W[(size_t)k * 256 + n] : (__bf16)0.0f;
            return;
        }
        i -= 256 * KPAD;
        if (i < D_EMB * 256) {                // embT [64][256]
            int n = i >> 8, k = i & 255;
            embT[i] = (__bf16)emb_W[(size_t)k * D_EMB + n];
            return;
        }
        i -= D_EMB * 256;
        if (i < F_HID * D_EMB) {              // d1T [32][64]
            int n = i >> 6, k = i & 63;
            d1T[i] = (__bf16)d1[(size_t)k * F_HID + n];
            return;
        }
        i -= F_HID * D_EMB;
        if (i < D_IN * F_HID) {               // d2T [1000][32]
            int n = i >> 5, k = i & 31;
            d2T[i] = (__bf16)d2[(size_t)k * D_IN + n];
        }
        return;
    }
    b -= WT_BLOCKS;
    {
        int i = b * 256 + threadIdx.x;
        if (i < N_NODES) cnt[i] = 0;
    }
}

// ---------------------------------------------------------------------------
// bf16 MFMA GEMM staging (m97 structure), XOR chunk swizzle.
// ---------------------------------------------------------------------------
__device__ __forceinline__ void stage_tile(
    __bf16* lds, const __bf16* __restrict__ g, int base, int maxr,
    int K, int k0, int rows, int w, int lane)
{
    const int rsub = lane >> 2;
    const int c    = lane & 3;
    for (int off = w * 1024; off < rows * 64; off += 4096) {
        int r  = (off >> 6) + rsub;
        int gr = base + r; gr = gr > maxr ? maxr : gr;
        int chunk = c ^ (r & 3);
        const __bf16* gp = g + (size_t)gr * K + k0 + chunk * 8;
        __builtin_amdgcn_global_load_lds(
            (const __attribute__((address_space(1))) void*)gp,
            (__attribute__((address_space(3))) void*)((char*)lds + off),
            16, 0, 0);
    }
}

template<int BM, int BN, int RELU>
__global__ __launch_bounds__(256) void gemm_bf16(
    const __bf16* __restrict__ A, const __bf16* __restrict__ Bt,
    float* __restrict__ Cf, __bf16* __restrict__ Cb,
    const float* __restrict__ bias, int M, int Nn, int K)
{
    constexpr int MT = BM / 32;
    constexpr int NT = BN / 32;
    __shared__ __align__(16) __bf16 As[BM * 32];
    __shared__ __align__(16) __bf16 Bs[BN * 32];

    const int tid  = threadIdx.x;
    const int w    = tid >> 6, lane = tid & 63;
    const int wm   = w >> 1,   wn   = w & 1;
    const int quad = lane >> 4, l16 = lane & 15;
    const int bm = blockIdx.x * BM, bn = blockIdx.y * BN;

    f32x4 acc[MT][NT];
    #pragma unroll
    for (int i = 0; i < MT; i++)
        #pragma unroll
        for (int j = 0; j < NT; j++)
            acc[i][j] = (f32x4){0.f, 0.f, 0.f, 0.f};

    for (int k0 = 0; k0 < K; k0 += 32) {
        stage_tile(As, A,  bm, M  - 1, K, k0, BM, w, lane);
        stage_tile(Bs, Bt, bn, Nn - 1, K, k0, BN, w, lane);
        __syncthreads();

        bf16x8 af[MT], bfr[NT];
        #pragma unroll
        for (int mt = 0; mt < MT; mt++) {
            int r = wm * 64 + mt * 16 + l16;
            af[mt] = *(const bf16x8*)&As[r * 32 + (quad ^ (r & 3)) * 8];
        }
        #pragma unroll
        for (int nt = 0; nt < NT; nt++) {
            int r = wn * (NT * 16) + nt * 16 + l16;
            bfr[nt] = *(const bf16x8*)&Bs[r * 32 + (quad ^ (r & 3)) * 8];
        }
        #pragma unroll
        for (int mt = 0; mt < MT; mt++)
            #pragma unroll
            for (int nt = 0; nt < NT; nt++)
                acc[mt][nt] = __builtin_amdgcn_mfma_f32_16x16x32_bf16(
                    af[mt], bfr[nt], acc[mt][nt], 0, 0, 0);
        __syncthreads();
    }

    #pragma unroll
    for (int nt = 0; nt < NT; nt++) {
        int col = bn + wn * (NT * 16) + nt * 16 + l16;
        if (col >= Nn) continue;
        float bv = bias ? bias[col] : 0.0f;
        #pragma unroll
        for (int mt = 0; mt < MT; mt++) {
            int row0 = bm + wm * 64 + mt * 16 + quad * 4;
            #pragma unroll
            for (int rr = 0; rr < 4; rr++) {
                int row = row0 + rr;
                if (row < M) {
                    float v = acc[mt][nt][rr] + bv;
                    if (RELU) v = v > 0.f ? v : 0.f;
                    if (Cf) Cf[(size_t)row * Nn + col] = v;
                    if (Cb) Cb[(size_t)row * Nn + col] = (__bf16)v;
                }
            }
        }
    }
}

// ---------------------------------------------------------------------------
// Fused: attention scores | padded-CSR edge scatter (independent block ranges)
// ---------------------------------------------------------------------------
#define ATT_BLOCKS ((N_NODES * NHEAD + 255) / 256)   // 938
#define SC_BLOCKS  ((N_EDGES + 255) / 256)           // 1875

__global__ __launch_bounds__(256) void att_scatter(
    const __bf16* __restrict__ hb, const float* __restrict__ att_src,
    const float* __restrict__ att_dst, const int* __restrict__ eidx,
    float* __restrict__ a_s, float* __restrict__ a_d,
    int* __restrict__ cnt, int* __restrict__ slots)
{
    int b = blockIdx.x;
    if (b < ATT_BLOCKS) {
        int i = b * 256 + threadIdx.x;
        if (i >= N_NODES * NHEAD) return;
        int hh = i & 7;
        const bf16x8* hp = (const bf16x8*)(hb + (size_t)i * F_HID);
        const float* sp = att_src + hh * F_HID;
        const float* dp = att_dst + hh * F_HID;
        float s = 0.f, d = 0.f;
        #pragma unroll
        for (int j = 0; j < 4; j++) {
            bf16x8 hv = hp[j];
            #pragma unroll
            for (int t = 0; t < 8; t++) {
                float f = (float)hv[t];
                s += f * sp[j * 8 + t];
                d += f * dp[j * 8 + t];
            }
        }
        a_s[i] = s;
        a_d[i] = d;
        return;
    }
    b -= ATT_BLOCKS;
    {
        int e = b * 256 + threadIdx.x;
        if (e < N_EDGES) {
            int d = eidx[N_EDGES + e];
            int slot = atomicAdd(&cnt[d], 1);
            slots[d * MAXDEG + slot] = eidx[e];
        }
    }
}

// ---------------------------------------------------------------------------
// GAT aggregation, single pass, padded CSR, x4-unrolled gathers.
// ---------------------------------------------------------------------------
__device__ __forceinline__ float leaky(float x) {
    return x > 0.f ? x : NEG_SLOPE * x;
}

__global__ __launch_bounds__(256) void gat_aggregate(
    const __bf16* __restrict__ hb, const float* __restrict__ a_s,
    const float* __restrict__ a_d, const int* __restrict__ cnt,
    const int* __restrict__ slots, const float* __restrict__ bias,
    __bf16* __restrict__ hgatb)
{
    const int wid  = threadIdx.x >> 6;
    const int lane = threadIdx.x & 63;
    const int n = blockIdx.x * 4 + wid;
    if (n >= N_NODES) return;

    const int hh = lane >> 3;
    const int fo = (lane & 7) * 4;
    const int base = n * MAXDEG;
    const int c = cnt[n];
    const float adn = a_d[n * NHEAD + hh];

    // self loop
    float p = __expf(leaky(a_s[n * NHEAD + hh] + adn));
    float denom = p;
    f32x4 acc;
    {
        bf16x4 hv = *(const bf16x4*)(hb + (size_t)n * 256 + hh * F_HID + fo);
        acc.x = p * (float)hv[0]; acc.y = p * (float)hv[1];
        acc.z = p * (float)hv[2]; acc.w = p * (float)hv[3];
    }
    int e = 0;
    for (; e + 4 <= c; e += 4) {
        int s0 = slots[base + e + 0];
        int s1 = slots[base + e + 1];
        int s2 = slots[base + e + 2];
        int s3 = slots[base + e + 3];
        float l0 = a_s[s0 * NHEAD + hh], l1 = a_s[s1 * NHEAD + hh];
        float l2 = a_s[s2 * NHEAD + hh], l3 = a_s[s3 * NHEAD + hh];
        bf16x4 h0 = *(const bf16x4*)(hb + (size_t)s0 * 256 + hh * F_HID + fo);
        bf16x4 h1 = *(const bf16x4*)(hb + (size_t)s1 * 256 + hh * F_HID + fo);
        bf16x4 h2 = *(const bf16x4*)(hb + (size_t)s2 * 256 + hh * F_HID + fo);
        bf16x4 h3 = *(const bf16x4*)(hb + (size_t)s3 * 256 + hh * F_HID + fo);
        float p0 = __expf(leaky(l0 + adn)), p1 = __expf(leaky(l1 + adn));
        float p2 = __expf(leaky(l2 + adn)), p3 = __expf(leaky(l3 + adn));
        denom += (p0 + p1) + (p2 + p3);
        acc.x += p0*(float)h0[0] + p1*(float)h1[0] + p2*(float)h2[0] + p3*(float)h3[0];
        acc.y += p0*(float)h0[1] + p1*(float)h1[1] + p2*(float)h2[1] + p3*(float)h3[1];
        acc.z += p0*(float)h0[2] + p1*(float)h1[2] + p2*(float)h2[2] + p3*(float)h3[2];
        acc.w += p0*(float)h0[3] + p1*(float)h1[3] + p2*(float)h2[3] + p3*(float)h3[3];
    }
    for (; e < c; e++) {
        int s = slots[base + e];
        float pe = __expf(leaky(a_s[s * NHEAD + hh] + adn));
        denom += pe;
        bf16x4 hv = *(const bf16x4*)(hb + (size_t)s * 256 + hh * F_HID + fo);
        acc.x += pe * (float)hv[0]; acc.y += pe * (float)hv[1];
        acc.z += pe * (float)hv[2]; acc.w += pe * (float)hv[3];
    }
    float inv = 1.0f / denom;
    f32x4 bv = *(const f32x4*)(bias + lane * 4);
    float o0 = acc.x * inv + bv.x, o1 = acc.y * inv + bv.y;
    float o2 = acc.z * inv + bv.z, o3 = acc.w * inv + bv.w;
    o0 = o0 > 0.f ? o0 : 0.f;
    o1 = o1 > 0.f ? o1 : 0.f;
    o2 = o2 > 0.f ? o2 : 0.f;
    o3 = o3 > 0.f ? o3 : 0.f;
    bf16x4 ob;
    ob[0] = (__bf16)o0; ob[1] = (__bf16)o1; ob[2] = (__bf16)o2; ob[3] = (__bf16)o3;
    *(bf16x4*)(hgatb + (size_t)n * 256 + lane * 4) = ob;
}

// ---------------------------------------------------------------------------
// Fused gemm2+gemm3: z = hgat@embT + emb_b (write fp32 z out, bf16 z to LDS),
// then d = relu(z@d1T + dec_b1) -> dbufb bf16. Block = 128 rows.
// ---------------------------------------------------------------------------
__global__ __launch_bounds__(256) void gemm_zd(
    const __bf16* __restrict__ hgatb, const __bf16* __restrict__ embT,
    const __bf16* __restrict__ d1T, const float* __restrict__ emb_b,
    const float* __restrict__ dec_b1, float* __restrict__ z,
    __bf16* __restrict__ dbufb, int M)
{
    __shared__ __align__(16) __bf16 As[128 * 32];   // 8KB
    __shared__ __align__(16) __bf16 Bs[64 * 32];    // 4KB
    __shared__ __align__(16) __bf16 zS[128 * 64];   // 16KB, 2 slices of [128][32]
    __shared__ __align__(16) __bf16 Bs2[2 * 32 * 32]; // 4KB, d1T 2 slices [32][32]

    const int tid  = threadIdx.x;
    const int w    = tid >> 6, lane = tid & 63;
    const int wm   = w >> 1,   wn   = w & 1;
    const int quad = lane >> 4, l16 = lane & 15;
    const int bm = blockIdx.x * 128;

    // stage d1T once: slice t = k-chunk t*32..t*32+31, rows n=0..31
    stage_tile(Bs2,        d1T, 0, 31, 64, 0,  32, w, lane);
    stage_tile(Bs2 + 1024, d1T, 0, 31, 64, 32, 32, w, lane);

    // ---- phase 1: z = hgat @ embT ----
    f32x4 acc[4][2];
    #pragma unroll
    for (int i = 0; i < 4; i++) { acc[i][0] = (f32x4){0,0,0,0}; acc[i][1] = (f32x4){0,0,0,0}; }

    for (int k0 = 0; k0 < 256; k0 += 32) {
        stage_tile(As, hgatb, bm, M - 1, 256, k0, 128, w, lane);
        stage_tile(Bs, embT,  0,  D_EMB - 1, 256, k0, 64, w, lane);
        __syncthreads();
        bf16x8 af[4], bfr[2];
        #pragma unroll
        for (int mt = 0; mt < 4; mt++) {
            int r = wm * 64 + mt * 16 + l16;
            af[mt] = *(const bf16x8*)&As[r * 32 + (quad ^ (r & 3)) * 8];
        }
        #pragma unroll
        for (int nt = 0; nt < 2; nt++) {
            int r = wn * 32 + nt * 16 + l16;
            bfr[nt] = *(const bf16x8*)&Bs[r * 32 + (quad ^ (r & 3)) * 8];
        }
        #pragma unroll
        for (int mt = 0; mt < 4; mt++)
            #pragma unroll
            for (int nt = 0; nt < 2; nt++)
                acc[mt][nt] = __builtin_amdgcn_mfma_f32_16x16x32_bf16(
                    af[mt], bfr[nt], acc[mt][nt], 0, 0, 0);
        __syncthreads();
    }

    // epilogue 1: z fp32 -> global out; z bf16 -> zS in stage_tile layout
    #pragma unroll
    for (int nt = 0; nt < 2; nt++) {
        int col = wn * 32 + nt * 16 + l16;
        float bv = emb_b[col];
        int t = col >> 5, cch = (col >> 3) & 3, j = col & 7;
        #pragma unroll
        for (int mt = 0; mt < 4; mt++) {
            int rl0 = wm * 64 + mt * 16 + quad * 4;
            #pragma unroll
            for (int rr = 0; rr < 4; rr++) {
                int rl = rl0 + rr;
                int row = bm + rl;
                float v = acc[mt][nt][rr] + bv;
                if (row < M) z[(size_t)row * D_EMB + col] = v;
                zS[t * 4096 + rl * 32 + (cch ^ (rl & 3)) * 8 + j] = (__bf16)v;
            }
        }
    }
    __syncthreads();

    // ---- phase 2: d = relu(zS @ d1T + b1), K=64 (2 slices), N=32 ----
    f32x4 accd[4];
    #pragma unroll
    for (int i = 0; i < 4; i++) accd[i] = (f32x4){0,0,0,0};
    #pragma unroll
    for (int t = 0; t < 2; t++) {
        bf16x8 af[4], bfr;
        #pragma unroll
        for (int mt = 0; mt < 4; mt++) {
            int r = wm * 64 + mt * 16 + l16;
            af[mt] = *(const bf16x8*)&zS[t * 4096 + r * 32 + (quad ^ (r & 3)) * 8];
        }
        {
            int r = wn * 16 + l16;
            bfr = *(const bf16x8*)&Bs2[t * 1024 + r * 32 + (quad ^ (r & 3)) * 8];
        }
        #pragma unroll
        for (int mt = 0; mt < 4; mt++)
            accd[mt] = __builtin_amdgcn_mfma_f32_16x16x32_bf16(af[mt], bfr, accd[mt], 0, 0, 0);
    }
    {
        int col = wn * 16 + l16;
        float bv = dec_b1[col];
        #pragma unroll
        for (int mt = 0; mt < 4; mt++) {
            int rl0 = wm * 64 + mt * 16 + quad * 4;
            #pragma unroll
            for (int rr = 0; rr < 4; rr++) {
                int row = bm + rl0 + rr;
                if (row < M) {
                    float v = accd[mt][rr] + bv;
                    v = v > 0.f ? v : 0.f;
                    dbufb[(size_t)row * F_HID + col] = (__bf16)v;
                }
            }
        }
    }
}

// ---------------------------------------------------------------------------
extern "C" void kernel_launch(void* const* d_in, const int* in_sizes, int n_in,
                              void* d_out, int out_size, void* d_ws, size_t ws_size,
                              hipStream_t stream)
{
    const float* x        = (const float*)d_in[0];
    const int*   eidx     = (const int*)  d_in[1];
    const float* W        = (const float*)d_in[3];
    const float* att_src  = (const float*)d_in[4];
    const float* att_dst  = (const float*)d_in[5];
    const float* bias_gat = (const float*)d_in[6];
    const float* emb_W    = (const float*)d_in[7];
    const float* emb_b    = (const float*)d_in[8];
    const float* dec_W1   = (const float*)d_in[9];
    const float* dec_b1   = (const float*)d_in[10];
    const float* dec_W2   = (const float*)d_in[11];
    const float* dec_b2   = (const float*)d_in[12];

    float* out   = (float*)d_out;
    float* recon = out;                             // [30000,1000] fp32
    float* z     = out + (size_t)N_NODES * D_IN;    // [30000,64]   fp32

    // xb (bf16 x padded to K=1024) lives in the recon region (dead before gemm4).
    __bf16* xb = (__bf16*)recon;

    char* ws = (char*)d_ws;
    size_t o = 0;
    auto alloc = [&](size_t bytes) { char* p = ws + o; o = (o + bytes + 255) & ~(size_t)255; return p; };
    __bf16* hb      = (__bf16*)alloc((size_t)N_NODES * 256 * 2);
    __bf16* WbT     = (__bf16*)alloc((size_t)256 * KPAD * 2);
    __bf16* embT    = (__bf16*)alloc((size_t)D_EMB * 256 * 2);
    __bf16* d1T     = (__bf16*)alloc((size_t)F_HID * D_EMB * 2);
    __bf16* d2T     = (__bf16*)alloc((size_t)D_IN * F_HID * 2);
    __bf16* hgatb   = (__bf16*)alloc((size_t)N_NODES * 256 * 2);
    __bf16* dbufb   = (__bf16*)alloc((size_t)N_NODES * F_HID * 2);
    float*  a_s     = (float*) alloc((size_t)N_NODES * NHEAD * 4);
    float*  a_d     = (float*) alloc((size_t)N_NODES * NHEAD * 4);
    int*    slots   = (int*)   alloc((size_t)N_NODES * MAXDEG * 4);
    int*    cnt     = (int*)   alloc((size_t)N_NODES * 4);

    const int MB = (N_NODES + 127) / 128;           // 235

    // 1. fused converts + cnt zero
    cvt_all<<<XB_BLOCKS + WT_BLOCKS + ZC_BLOCKS, 256, 0, stream>>>(
        x, W, emb_W, dec_W1, dec_W2, xb, WbT, embT, d1T, d2T, cnt);

    // 2. h = x @ W -> hb bf16
    gemm_bf16<128, 128, 0><<<dim3(MB, 2), 256, 0, stream>>>(
        xb, WbT, (float*)nullptr, hb, (const float*)nullptr, N_NODES, 256, KPAD);

    // 3. attention scores + padded-CSR scatter (fused)
    att_scatter<<<ATT_BLOCKS + SC_BLOCKS, 256, 0, stream>>>(
        hb, att_src, att_dst, eidx, a_s, a_d, cnt, slots);

    // 4. GAT aggregation -> hgatb bf16
    gat_aggregate<<<N_NODES / 4, 256, 0, stream>>>(
        hb, a_s, a_d, cnt, slots, bias_gat, hgatb);

    // 5. fused z + d
    gemm_zd<<<MB, 256, 0, stream>>>(
        hgatb, embT, d1T, emb_b, dec_b1, z, dbufb, N_NODES);

    // 6. recon = d @ dec_W2 + dec_b2 (overwrites xb region)
    gemm_bf16<128, 128, 0><<<dim3(MB, 8), 256, 0, stream>>>(
        dbufb, d2T, recon, (__bf16*)nullptr, dec_b2, N_NODES, D_IN, F_HID);
}